// Round 1
// 453.245 us; speedup vs baseline: 1.1439x; 1.1439x over previous
//
#include <hip/hip_runtime.h>
#include <cstdint>
#include <cstddef>

// Problem constants: B=128, L=64, F=3072, D=1024, CV=512, CN=1024, MAX_K=8
typedef unsigned short u16;
typedef __attribute__((ext_vector_type(8))) short short8;   // 8 x bf16 (4 VGPRs)
typedef __attribute__((ext_vector_type(4))) float f32x4;    // MFMA accumulator

static __device__ __forceinline__ float bf2f(u16 h) {
  union { unsigned u; float f; } a; a.u = ((unsigned)h) << 16; return a.f;
}
static __device__ __forceinline__ u16 f2bf(float x) {
  union { float f; unsigned u; } a; a.f = x;
  return (u16)((a.u + 0x7fffu + ((a.u >> 16) & 1u)) >> 16);  // RNE
}

// async global->LDS, 16B per lane. LDS dest is wave-uniform base + lane*16.
#define GLDS16(gp, lp)                                                          \
  __builtin_amdgcn_global_load_lds(                                             \
      (const __attribute__((address_space(1))) void*)(gp),                      \
      (__attribute__((address_space(3))) void*)(lp), 16, 0, 0)

// ------------------------------------------------------------- merged prep
// blocks [0,24576): cast inputs fp32->bf16
// blocks [24576,33792): transpose [W0|W1|W2] -> Wt (N-major bf16)
// blocks [33792,34304): prep verb conv weights (BN folded)
// blocks [34304,35328): prep noun conv weights (BN folded)
// blocks [35328,36352): zero pad rows of e1pad
__global__ void prep_all(const float* __restrict__ inputs, u16* __restrict__ Xbf,
                         const float* __restrict__ W0, const float* __restrict__ W1,
                         const float* __restrict__ W2, u16* __restrict__ Wt,
                         const float* __restrict__ Kv, const float* __restrict__ bv,
                         const float* __restrict__ g_v, const float* __restrict__ beta_v,
                         const float* __restrict__ mean_v, const float* __restrict__ var_v,
                         u16* __restrict__ KVt, float* __restrict__ biasv,
                         const float* __restrict__ Kn, const float* __restrict__ bnb,
                         const float* __restrict__ g_n, const float* __restrict__ beta_n,
                         const float* __restrict__ mean_n, const float* __restrict__ var_n,
                         u16* __restrict__ KNt, float* __restrict__ biasn,
                         u16* __restrict__ e1pad) {
  __shared__ float tile[32][33];
  const int id = blockIdx.x;
  const int tid = threadIdx.x;
  if (id < 24576) {                       // cast: float4 -> 4x bf16
    const int i = id * 256 + tid;         // < 6291456 exactly
    float4 v = ((const float4*)inputs)[i];
    ushort4 o;
    o.x = f2bf(v.x); o.y = f2bf(v.y); o.z = f2bf(v.z); o.w = f2bf(v.w);
    ((ushort4*)Xbf)[i] = o;
  } else if (id < 33792) {                // transpose W
    const int idd = id - 24576;
    const int kb = (idd % 96) * 32;
    const int jb = (idd / 96) * 32;
    const int tx = tid & 31, ty = tid >> 5;
    const int w = jb >> 10;
    const float* W = (w == 0) ? W0 : ((w == 1) ? W1 : W2);
    const int nb = jb & 1023;
    for (int i = ty; i < 32; i += 8)
      tile[i][tx] = W[(size_t)(kb + i) * 1024 + nb + tx];
    __syncthreads();
    for (int i = ty; i < 32; i += 8)
      Wt[(size_t)(jb + i) * 3072 + kb + tx] = f2bf(tile[tx][i]);
  } else if (id < 34304) {                // prep_kv
    const int c = id - 33792;
    const float scale = g_v[c] * rsqrtf(var_v[c] + 1e-5f);
    for (int t = 0; t < 3; t++)
      for (int d = tid; d < 1024; d += 256)
        KVt[(size_t)c * 3072 + t * 1024 + d] = f2bf(Kv[(size_t)c * 3072 + d * 3 + t] * scale);
    if (tid == 0) biasv[c] = (bv[c] - mean_v[c]) * scale + beta_v[c];
  } else if (id < 35328) {                // prep_kn
    const int c = id - 34304;
    const float scale = g_n[c] * rsqrtf(var_n[c] + 1e-5f);
    for (int d = tid; d < 1024; d += 256)
      KNt[(size_t)c * 1024 + d] = f2bf(Kn[(size_t)c * 1024 + d] * scale);
    if (tid == 0) biasn[c] = (bnb[c] - mean_n[c]) * scale + beta_n[c];
  } else {                                // zero pad rows 0,65 of e1pad (B,66,D)
    const int i = (id - 35328) * 256 + tid;   // 0..262143
    const int b = i >> 11;
    const int j = i & 2047;
    const int r = (j < 1024) ? 0 : 65;
    const int d = j & 1023;
    e1pad[(size_t)(b * 66 + r) * 1024 + d] = 0;
  }
}

// =====================================================================
// Pipelined GEMM core (T2+T3+T4+T5): BM=128, BN=256, BK=64, 512 threads
// = 8 waves (2M x 4N), per-wave 64x64 output via 4x4 mfma_f32_16x16x32_bf16.
//
// LDS: 3-slot ring, 48 KB/slot (A 128x64 bf16 = 8192 u16, B 256x64 = 16384
// u16). Tile t computed from slot t%3 while tiles t+1,t+2 stream in via
// global_load_lds. 6 GLDS/tile (A-half0, A-half1, B-q0 in phase 1;
// B-q1..3 in phase 2). One counted s_waitcnt vmcnt(6) per K-tile (never 0
// in the main loop): guarantees tile t+1 staged, leaves tile t+2's 6 loads
// in flight across the barrier.
//
// LDS swizzle: per row (128 B = 8 chunks of 16 B), chunk c stored at
// position (c + row)&7 -> every 8-lane group of a ds_read_b128 hits all 8
// bank-groups (0-conflict). Staging keeps the LDS dest linear and
// pre-swizzles the per-lane GLOBAL source (chunk (pos - row)&7).
//
// Per phase: 8x ds_read_b128 + 3x global_load_lds -> s_barrier ->
// lgkmcnt(0) -> setprio(1) -> 16 MFMA -> setprio(0) -> s_barrier.
// No __syncthreads() in the loop (it would emit the vmcnt(0) drain).
// =====================================================================
#define SLOT 24576   // u16 per ring slot (48 KB)

#define MFMA16_()                                                                  \
  acc[0][0] = __builtin_amdgcn_mfma_f32_16x16x32_bf16(a0, b0, acc[0][0], 0, 0, 0); \
  acc[0][1] = __builtin_amdgcn_mfma_f32_16x16x32_bf16(a0, b1, acc[0][1], 0, 0, 0); \
  acc[0][2] = __builtin_amdgcn_mfma_f32_16x16x32_bf16(a0, b2, acc[0][2], 0, 0, 0); \
  acc[0][3] = __builtin_amdgcn_mfma_f32_16x16x32_bf16(a0, b3, acc[0][3], 0, 0, 0); \
  acc[1][0] = __builtin_amdgcn_mfma_f32_16x16x32_bf16(a1, b0, acc[1][0], 0, 0, 0); \
  acc[1][1] = __builtin_amdgcn_mfma_f32_16x16x32_bf16(a1, b1, acc[1][1], 0, 0, 0); \
  acc[1][2] = __builtin_amdgcn_mfma_f32_16x16x32_bf16(a1, b2, acc[1][2], 0, 0, 0); \
  acc[1][3] = __builtin_amdgcn_mfma_f32_16x16x32_bf16(a1, b3, acc[1][3], 0, 0, 0); \
  acc[2][0] = __builtin_amdgcn_mfma_f32_16x16x32_bf16(a2, b0, acc[2][0], 0, 0, 0); \
  acc[2][1] = __builtin_amdgcn_mfma_f32_16x16x32_bf16(a2, b1, acc[2][1], 0, 0, 0); \
  acc[2][2] = __builtin_amdgcn_mfma_f32_16x16x32_bf16(a2, b2, acc[2][2], 0, 0, 0); \
  acc[2][3] = __builtin_amdgcn_mfma_f32_16x16x32_bf16(a2, b3, acc[2][3], 0, 0, 0); \
  acc[3][0] = __builtin_amdgcn_mfma_f32_16x16x32_bf16(a3, b0, acc[3][0], 0, 0, 0); \
  acc[3][1] = __builtin_amdgcn_mfma_f32_16x16x32_bf16(a3, b1, acc[3][1], 0, 0, 0); \
  acc[3][2] = __builtin_amdgcn_mfma_f32_16x16x32_bf16(a3, b2, acc[3][2], 0, 0, 0); \
  acc[3][3] = __builtin_amdgcn_mfma_f32_16x16x32_bf16(a3, b3, acc[3][3], 0, 0, 0);

#define KTILE_(CUR, NXT, T)                                                     \
  {                                                                             \
    const int t_ = (T);                                                         \
    const bool st_ = (t_ + 2 < NT);                                             \
    const size_t kk_ = (size_t)(t_ + 2) * 64;                                   \
    { /* phase 1: ks = 0 */                                                     \
      const u16* ra = rdA + (CUR) * SLOT;                                       \
      const u16* rb = rdB + (CUR) * SLOT;                                       \
      short8 a0 = *(const short8*)(ra + p0);                                    \
      short8 a1 = *(const short8*)(ra + 1024 + p0);                             \
      short8 a2 = *(const short8*)(ra + 2048 + p0);                             \
      short8 a3 = *(const short8*)(ra + 3072 + p0);                             \
      short8 b0 = *(const short8*)(rb + p0);                                    \
      short8 b1 = *(const short8*)(rb + 1024 + p0);                             \
      short8 b2 = *(const short8*)(rb + 2048 + p0);                             \
      short8 b3 = *(const short8*)(rb + 3072 + p0);                             \
      if (st_) {                                                                \
        GLDS16(gA + kk_, stA + (NXT) * SLOT);                                   \
        GLDS16(gA + hA + kk_, stA + (NXT) * SLOT + 4096);                       \
        GLDS16(gB + kk_, stB + (NXT) * SLOT);                                   \
      }                                                                         \
      __builtin_amdgcn_s_barrier();                                             \
      asm volatile("s_waitcnt lgkmcnt(0)" ::: "memory");                        \
      __builtin_amdgcn_s_setprio(1);                                            \
      MFMA16_();                                                                \
      __builtin_amdgcn_s_setprio(0);                                            \
      __builtin_amdgcn_s_barrier();                                             \
    }                                                                           \
    { /* phase 2: ks = 1 */                                                     \
      const u16* ra = rdA + (CUR) * SLOT;                                       \
      const u16* rb = rdB + (CUR) * SLOT;                                       \
      short8 a0 = *(const short8*)(ra + p1);                                    \
      short8 a1 = *(const short8*)(ra + 1024 + p1);                             \
      short8 a2 = *(const short8*)(ra + 2048 + p1);                             \
      short8 a3 = *(const short8*)(ra + 3072 + p1);                             \
      short8 b0 = *(const short8*)(rb + p1);                                    \
      short8 b1 = *(const short8*)(rb + 1024 + p1);                             \
      short8 b2 = *(const short8*)(rb + 2048 + p1);                             \
      short8 b3 = *(const short8*)(rb + 3072 + p1);                             \
      if (st_) {                                                                \
        GLDS16(gB + hB + kk_, stB + (NXT) * SLOT + 4096);                       \
        GLDS16(gB + 2 * hB + kk_, stB + (NXT) * SLOT + 8192);                   \
        GLDS16(gB + 3 * hB + kk_, stB + (NXT) * SLOT + 12288);                  \
      }                                                                         \
      __builtin_amdgcn_s_barrier();                                             \
      asm volatile("s_waitcnt lgkmcnt(0)" ::: "memory");                        \
      __builtin_amdgcn_s_setprio(1);                                            \
      MFMA16_();                                                                \
      __builtin_amdgcn_s_setprio(0);                                            \
      if (t_ < NT - 2) {                                                        \
        asm volatile("s_waitcnt vmcnt(6)" ::: "memory");                        \
      } else if (t_ == NT - 2) {                                                \
        asm volatile("s_waitcnt vmcnt(0)" ::: "memory");                        \
      }                                                                         \
      __builtin_amdgcn_s_barrier();                                             \
    }                                                                           \
  }

// gA: per-thread staged A base = Aglob + (row u)*ldA + c8 ; hA = 64*ldA
// gB: per-thread staged B base = Bglob + (row u)*ldB + c8 ; hB = 64*ldB
template<int NT>
static __device__ __forceinline__ void gemm_pipe(
    const u16* __restrict__ gA, const size_t hA,
    const u16* __restrict__ gB, const size_t hB,
    u16* lds, f32x4 (&acc)[4][4]) {
  const int tid = threadIdx.x;
  const int lane = tid & 63;
  const int warp = tid >> 6;
  const int wm = warp & 1, wn = warp >> 1;
  const int l15 = lane & 15, quad = lane >> 4;

  u16* stA = lds + tid * 8;                          // linear GLDS dest (A)
  u16* stB = lds + 8192 + tid * 8;                   // linear GLDS dest (B)
  const u16* rdA = lds + (wm * 64 + l15) * 64;       // fragment read bases
  const u16* rdB = lds + 8192 + (wn * 64 + l15) * 64;
  const int p0 = ((quad + l15) & 7) * 8;             // swizzled k-chunk, ks=0
  const int p1 = p0 ^ 32;                            // ks=1 ((x+4)&7 == x^4)

  // prologue: stage tiles 0,1 into slots 0,1 (6 loads each, A0,A1,B0..B3)
#pragma unroll
  for (int s = 0; s < 2; s++) {
    const size_t kk = (size_t)s * 64;
    GLDS16(gA + kk, stA + s * SLOT);
    GLDS16(gA + hA + kk, stA + s * SLOT + 4096);
    GLDS16(gB + kk, stB + s * SLOT);
    GLDS16(gB + hB + kk, stB + s * SLOT + 4096);
    GLDS16(gB + 2 * hB + kk, stB + s * SLOT + 8192);
    GLDS16(gB + 3 * hB + kk, stB + s * SLOT + 12288);
  }
  asm volatile("s_waitcnt vmcnt(6)" ::: "memory");   // tile 0 landed; tile 1 in flight
  __builtin_amdgcn_s_barrier();

#pragma unroll 1
  for (int t = 0; t < NT; t += 3) {                  // slots compile-time via x3 unroll
    KTILE_(0, 2, t);
    if (t + 1 < NT) KTILE_(1, 0, t + 1);
    if (t + 2 < NT) KTILE_(2, 1, t + 2);
  }
}

// epilogue: sigmoid + per-column top-8 + mean of top-k (per-wave batch)
static __device__ __forceinline__ void topk_epilogue(
    f32x4 (&acc)[4][4], const float* __restrict__ bias,
    const int* __restrict__ lens, float* __restrict__ out,
    const int NC, const int m0, const int n0) {
  const int tid = threadIdx.x;
  const int lane = tid & 63;
  const int warp = tid >> 6;
  const int wm = warp & 1, wn = warp >> 1;
  const int l15 = lane & 15, quad = lane >> 4;
  const int b = (m0 >> 6) + wm;            // this wave's batch
  const int len = lens[b];
  const int kk8 = (len + 7) >> 3;          // k = ceil(len/8), 1..8
#pragma unroll
  for (int j = 0; j < 4; j++) {
    const int c = n0 + wn * 64 + j * 16 + l15;
    const float bias_c = bias[c];
    float t[8];
#pragma unroll
    for (int q8 = 0; q8 < 8; q8++) t[q8] = -1e30f;
#pragma unroll
    for (int i = 0; i < 4; i++) {
#pragma unroll
      for (int r = 0; r < 4; r++) {
        const int l = i * 16 + quad * 4 + r;
        const float v = acc[i][j][r] + bias_c;
        const float sg = 1.0f / (1.0f + __expf(-v));
        float x = (l < len) ? sg : -1e30f;
#pragma unroll
        for (int q8 = 0; q8 < 8; q8++) {   // branchless sorted insert (desc)
          const float hi = fmaxf(t[q8], x);
          x = fminf(t[q8], x);
          t[q8] = hi;
        }
      }
    }
    // merge top-8 lists across the 4 quads (lanes ^16, ^32).
    // SNAPSHOT the partner's entire list BEFORE inserting anything.
#pragma unroll
    for (int mask = 16; mask <= 32; mask <<= 1) {
      float xs[8];
#pragma unroll
      for (int q8 = 0; q8 < 8; q8++) xs[q8] = __shfl_xor(t[q8], mask);
#pragma unroll
      for (int q8 = 0; q8 < 8; q8++) {
        float x = xs[q8];
#pragma unroll
        for (int p8 = 0; p8 < 8; p8++) {
          const float hi = fmaxf(t[p8], x);
          x = fminf(t[p8], x);
          t[p8] = hi;
        }
      }
    }
    if (quad == 0) {
      float s = 0.f;
#pragma unroll
      for (int q8 = 0; q8 < 8; q8++) s += (q8 < kk8) ? t[q8] : 0.f;
      out[(size_t)b * NC + c] = s / (float)kk8;
    }
  }
}

// ------------------------------------------------------------------ embed GEMM
// grid (12, 64): bx = N-tile (256 cols), by = M-tile (128 rows). 768 blocks
// = 3 exact rounds of 256 CUs at 1 block/CU (144 KB LDS).
__global__ __launch_bounds__(512, 2) void gemm_embed(
    const u16* __restrict__ A, const u16* __restrict__ Bmat,
    const float* __restrict__ bias0, const float* __restrict__ bias1,
    const float* __restrict__ bias2,
    float* __restrict__ oute1, float* __restrict__ oute2,
    u16* __restrict__ e0bf, u16* __restrict__ e1pad, u16* __restrict__ e2bf) {
  __shared__ __align__(16) u16 lds[3 * SLOT];
  const int tid = threadIdx.x;
  const int m0 = blockIdx.y * 128;
  const int n0 = blockIdx.x * 256;
  const int u = tid >> 3;                           // staged row within 64-group
  const int c8 = (((tid & 7) - u) & 7) * 8;         // pre-swizzled global chunk

  f32x4 acc[4][4];
#pragma unroll
  for (int i = 0; i < 4; i++)
#pragma unroll
    for (int j = 0; j < 4; j++) acc[i][j] = (f32x4){0.f, 0.f, 0.f, 0.f};

  gemm_pipe<48>(A + (size_t)(m0 + u) * 3072 + c8, (size_t)64 * 3072,
                Bmat + (size_t)(n0 + u) * 3072 + c8, (size_t)64 * 3072,
                lds, acc);

  const int lane = tid & 63;
  const int warp = tid >> 6;
  const int wm = warp & 1, wn = warp >> 1;
  const int l15 = lane & 15, quad = lane >> 4;
  const int w = n0 >> 10;                           // block fits in one embed
  const float* bp = (w == 0) ? bias0 : ((w == 1) ? bias1 : bias2);
#pragma unroll
  for (int i = 0; i < 4; i++) {
    const int mrow = m0 + wm * 64 + i * 16 + quad * 4;
#pragma unroll
    for (int j = 0; j < 4; j++) {
      const int c = n0 + wn * 64 + j * 16 + l15;
      const int n = c & 1023;
      const float bias = bp[n];
#pragma unroll
      for (int r = 0; r < 4; r++) {
        const int m = mrow + r;
        const float v = acc[i][j][r] + bias;
        if (w == 0) {
          e0bf[(size_t)m * 1024 + n] = f2bf(v);
        } else if (w == 1) {
          oute1[(size_t)m * 1024 + n] = v;
          const int bb = m >> 6, ll = m & 63;
          e1pad[(size_t)(bb * 66 + ll + 1) * 1024 + n] = f2bf(v);
        } else {
          oute2[(size_t)m * 1024 + n] = v;
          e2bf[(size_t)m * 1024 + n] = f2bf(v);
        }
      }
    }
  }
}

// fused tail: blocks [0,128) verb GEMM+topk (NC=512, K=3072 im2col);
// [128,384) noun GEMM+topk (NC=1024, K=1024); [384,512) attention pooling.
__global__ __launch_bounds__(512, 2) void fused_tail(
    const u16* __restrict__ e1pad, const u16* __restrict__ KVt,
    const float* __restrict__ biasv,
    const u16* __restrict__ e2bf, const u16* __restrict__ KNt,
    const float* __restrict__ biasn,
    const u16* __restrict__ e0bf, const float* __restrict__ w_attn,
    const float* __restrict__ b_attn, const int* __restrict__ lens,
    float* __restrict__ out_sent, float* __restrict__ out_ilv,
    float* __restrict__ out_iln) {
  __shared__ __align__(16) u16 smem[3 * SLOT];
  const int id = blockIdx.x;
  const int tid = threadIdx.x;
  if (id < 384) {
    const int u = tid >> 3;
    const int c8 = (((tid & 7) - u) & 7) * 8;
    f32x4 acc[4][4];
#pragma unroll
    for (int i = 0; i < 4; i++)
#pragma unroll
      for (int j = 0; j < 4; j++) acc[i][j] = (f32x4){0.f, 0.f, 0.f, 0.f};
    if (id < 128) {
      // verb: A rows r=h*64+u -> e1pad[(by*2 + h)*66 + u]; kk=t2*64 is
      // segment-exact (1024 = 16*64), so im2col stays affine in kk.
      const int by = id >> 1, bx = id & 1;
      const int n0 = bx * 256;
      gemm_pipe<48>(e1pad + ((size_t)(by * 2) * 66 + u) * 1024 + c8, (size_t)66 * 1024,
                    KVt + (size_t)(n0 + u) * 3072 + c8, (size_t)64 * 3072,
                    smem, acc);
      topk_epilogue(acc, biasv, lens, out_ilv, 512, by * 128, n0);
    } else {
      const int id2 = id - 128;
      const int by = id2 >> 2, bx = id2 & 3;
      const int m0 = by * 128, n0 = bx * 256;
      gemm_pipe<16>(e2bf + (size_t)(m0 + u) * 1024 + c8, (size_t)64 * 1024,
                    KNt + (size_t)(n0 + u) * 1024 + c8, (size_t)64 * 1024,
                    smem, acc);
      topk_epilogue(acc, biasn, lens, out_iln, 1024, m0, n0);
    }
  } else {
    // ---- attention pooling, one block per batch (only 256 threads active
    // in the gated sections; barriers reached by all 512).
    const int b = id - 384;
    const int lane = tid & 63;
    const int warp = tid >> 6;
    float* sc = (float*)smem;        // 64 floats
    float* at = sc + 64;             // 64 floats
    const int len = lens[b];
    if (warp < 4) {
      for (int t = 0; t < 16; t++) {
        const int l = warp * 16 + t;
        const u16* row = e0bf + (size_t)(b * 64 + l) * 1024;
        float s = 0.f;
#pragma unroll
        for (int uu = 0; uu < 16; uu++) {
          const int d = lane + uu * 64;
          s += bf2f(row[d]) * w_attn[d];
        }
#pragma unroll
        for (int off = 32; off > 0; off >>= 1) s += __shfl_down(s, off);
        if (lane == 0) sc[l] = s + b_attn[0];
      }
    }
    __syncthreads();
    if (warp == 0) {
      float v = (lane < len) ? sc[lane] : -1e30f;
      float m = v;
#pragma unroll
      for (int off = 32; off > 0; off >>= 1) m = fmaxf(m, __shfl_xor(m, off));
      float p = (lane < len) ? __expf(v - m) : 0.f;
      float ssum = p;
#pragma unroll
      for (int off = 32; off > 0; off >>= 1) ssum += __shfl_xor(ssum, off);
      at[lane] = p / ssum;
    }
    __syncthreads();
    if (tid < 256) {
      const int d0 = tid * 4;
      float a0 = 0.f, a1 = 0.f, a2 = 0.f, a3 = 0.f;
      for (int l = 0; l < 64; l++) {
        const float wgt = at[l];
        const ushort4 u4 = *(const ushort4*)(e0bf + (size_t)(b * 64 + l) * 1024 + d0);
        a0 += wgt * bf2f(u4.x);
        a1 += wgt * bf2f(u4.y);
        a2 += wgt * bf2f(u4.z);
        a3 += wgt * bf2f(u4.w);
      }
      float4 o; o.x = a0; o.y = a1; o.z = a2; o.w = a3;
      *(float4*)(out_sent + (size_t)b * 1024 + d0) = o;
    }
  }
}

// --------------------------------------------------------------------- launch
extern "C" void kernel_launch(void* const* d_in, const int* in_sizes, int n_in,
                              void* d_out, int out_size, void* d_ws, size_t ws_size,
                              hipStream_t stream) {
  const float* inputs = (const float*)d_in[0];
  const int*   lens   = (const int*)d_in[1];
  const float* W0 = (const float*)d_in[2];
  const float* b0 = (const float*)d_in[3];
  const float* W1 = (const float*)d_in[4];
  const float* b1 = (const float*)d_in[5];
  const float* W2 = (const float*)d_in[6];
  const float* b2 = (const float*)d_in[7];
  const float* w_attn = (const float*)d_in[8];
  const float* b_attn = (const float*)d_in[9];
  const float* Kv   = (const float*)d_in[10];
  const float* bv   = (const float*)d_in[11];
  const float* g_v  = (const float*)d_in[12];
  const float* beta_v = (const float*)d_in[13];
  const float* mean_v = (const float*)d_in[14];
  const float* var_v  = (const float*)d_in[15];
  const float* Kn   = (const float*)d_in[16];
  const float* bn_b = (const float*)d_in[17];
  const float* g_n  = (const float*)d_in[18];
  const float* beta_n = (const float*)d_in[19];
  const float* mean_n = (const float*)d_in[20];
  const float* var_n  = (const float*)d_in[21];

  float* out = (float*)d_out;
  float* out_sent = out;                               // (128,1024)
  float* out_e1   = out + 131072;                      // (128,64,1024)
  float* out_e2   = out + 131072 + 8388608;            // (128,64,1024)
  float* out_ilv  = out + 131072 + 2 * 8388608;        // (128,512)
  float* out_iln  = out_ilv + 65536;                   // (128,1024)

  // workspace carve
  char* p = (char*)d_ws;
  u16* Xbf  = (u16*)p; p += (size_t)8192 * 3072 * 2;   // inputs bf16
  u16* Wt   = (u16*)p; p += (size_t)3072 * 3072 * 2;   // [W0|W1|W2]^T, N-major
  u16* KVt  = (u16*)p; p += (size_t)512 * 3072 * 2;    // verb weights, BN-folded
  u16* KNt  = (u16*)p; p += (size_t)1024 * 1024 * 2;   // noun weights, BN-folded
  float* biasv = (float*)p; p += 512 * 4;
  float* biasn = (float*)p; p += 1024 * 4;
  u16* e0bf  = (u16*)p; p += (size_t)8192 * 1024 * 2;
  u16* e1pad = (u16*)p; p += (size_t)128 * 66 * 1024 * 2;  // (B,66,D) zero-padded
  u16* e2bf  = (u16*)p; p += (size_t)8192 * 1024 * 2;

  prep_all<<<36352, 256, 0, stream>>>(inputs, Xbf, W0, W1, W2, Wt,
                                      Kv, bv, g_v, beta_v, mean_v, var_v, KVt, biasv,
                                      Kn, bn_b, g_n, beta_n, mean_n, var_n, KNt, biasn,
                                      e1pad);
  gemm_embed<<<dim3(12, 64), 512, 0, stream>>>(Xbf, Wt, b0, b1, b2, out_e1, out_e2,
                                               e0bf, e1pad, e2bf);
  fused_tail<<<512, 512, 0, stream>>>(e1pad, KVt, biasv, e2bf, KNt, biasn,
                                      e0bf, w_attn, b_attn, lens,
                                      out_sent, out_ilv, out_iln);
}